// Round 4
// baseline (682.095 us; speedup 1.0000x reference)
//
#include <hip/hip_runtime.h>
#include <hip/hip_cooperative_groups.h>
#include <cstdint>
#include <cstddef>

namespace cg = cooperative_groups;

// Problem constants
#define RN 12800   // routes
#define CN 25      // caps
#define ON 64      // out channels
#define IN_ 8      // in channels
#define BN 8       // batch
#define SOUT (BN*CN*ON)   // 12800 output elems

#define RPC 64            // routes per chunk
#define NRC (RN / RPC)    // 200 chunks
#define NWU (5 * NRC)     // 1000 pass work-units (5 c-groups x 200 chunks)
#define NFIN (BN * CN)    // 200 finalize work-units (b,c pairs)

typedef float    f4x  __attribute__((ext_vector_type(4)));
typedef uint32_t u4x  __attribute__((ext_vector_type(4)));

// ---- bf16 helpers (RNE) ----
__device__ __forceinline__ uint32_t pack_bf16(float a, float b) {
    uint32_t ua = __float_as_uint(a);
    uint32_t ub = __float_as_uint(b);
    ua = (ua + 0x7fffu + ((ua >> 16) & 1u)) >> 16;          // bf16(a) low half
    ub = (ub + 0x7fffu + ((ub >> 16) & 1u)) & 0xffff0000u;  // bf16(b) high half
    return ua | ub;
}
__device__ __forceinline__ float lo_bf16(uint32_t q) { return __uint_as_float(q << 16); }
__device__ __forceinline__ float hi_bf16(uint32_t q) { return __uint_as_float(q & 0xffff0000u); }

union SMem {
    float xs[RPC][BN][IN_];   // 16 KB x-stage
    float red[320];           // finalize reduction
};

// ============================================================================
// Phase: pass0 — u = W·x, acc S0 (uniform c), store u as bf16 (nontemporal).
// wu = bx*NRC-order: chunk = wu % NRC, bx = wu / NRC; wave owns c = bx*5+wave.
// ============================================================================
__device__ __forceinline__ void phase_pass0(
    const float* __restrict__ x, const float* __restrict__ W,
    float* __restrict__ Sp, uint32_t* __restrict__ U,
    SMem& sm, int nb, int bid)
{
    const int t = threadIdx.x, wave = t >> 6, lane = t & 63;
    for (int wu = bid; wu < NWU; wu += nb) {
        const int chunk = wu % NRC, bx = wu / NRC;
        const int r0 = chunk * RPC;
        const int c = bx * 5 + wave;
        __syncthreads();
        for (int s = t; s < RPC * BN * 2; s += 320) {
            const int i4 = s & 1, rl = (s >> 1) & (RPC - 1), b = s >> 7;
            *reinterpret_cast<float4*>(&sm.xs[rl][b][i4 * 4]) =
                *reinterpret_cast<const float4*>(
                    x + (((size_t)b * RN + r0 + rl) * IN_) + i4 * 4);
        }
        __syncthreads();

        float acc[BN];
        #pragma unroll
        for (int b = 0; b < BN; ++b) acc[b] = 0.f;

        #pragma unroll 2
        for (int rl = 0; rl < RPC; ++rl) {
            const int r = r0 + rl;
            const f4x* wp = reinterpret_cast<const f4x*>(
                W + ((((size_t)r * CN + c) * ON + lane) * IN_));
            const f4x w0 = __builtin_nontemporal_load(wp);
            const f4x w1 = __builtin_nontemporal_load(wp + 1);

            float u[BN];
            #pragma unroll
            for (int b = 0; b < BN; ++b) {
                const float4 xa = *reinterpret_cast<const float4*>(&sm.xs[rl][b][0]);
                const float4 xb = *reinterpret_cast<const float4*>(&sm.xs[rl][b][4]);
                u[b] = w0.x*xa.x + w0.y*xa.y + w0.z*xa.z + w0.w*xa.w
                     + w1.x*xb.x + w1.y*xb.y + w1.z*xb.z + w1.w*xb.w;
                acc[b] += u[b];
            }
            u4x q;
            q.x = pack_bf16(u[0], u[1]);
            q.y = pack_bf16(u[2], u[3]);
            q.z = pack_bf16(u[4], u[5]);
            q.w = pack_bf16(u[6], u[7]);
            __builtin_nontemporal_store(q, reinterpret_cast<u4x*>(
                U + (((size_t)r * CN + c) * ON + lane) * 4));
        }
        float* sp = Sp + (size_t)chunk * SOUT;
        #pragma unroll
        for (int b = 0; b < BN; ++b)
            sp[(b * CN + c) * ON + lane] = acc[b];
    }
}

// ============================================================================
// Phase: passU — read bf16 u_hat. MODE 1: b1 = mean_b<u,v0> (store), e=exp(b1).
// MODE 2: b2 = b1(load) + mean_b<u,v1>. acc += e*u, z += e.
// ============================================================================
template<int MODE>
__device__ __forceinline__ void phase_passU(
    const uint32_t* __restrict__ U, const float* __restrict__ vin,
    const float* __restrict__ bin, float* __restrict__ bout,
    float* __restrict__ Sp, float* __restrict__ Zp, int nb, int bid)
{
    const int t = threadIdx.x, wave = t >> 6, lane = t & 63;
    for (int wu = bid; wu < NWU; wu += nb) {
        const int chunk = wu % NRC, bx = wu / NRC;
        const int r0 = chunk * RPC;
        const int c = bx * 5 + wave;

        float vreg[BN];
        #pragma unroll
        for (int b = 0; b < BN; ++b)
            vreg[b] = vin[(b * CN + c) * ON + lane];

        float acc[BN];
        #pragma unroll
        for (int b = 0; b < BN; ++b) acc[b] = 0.f;
        float zacc = 0.f;

        #pragma unroll 2
        for (int rl = 0; rl < RPC; ++rl) {
            const int r = r0 + rl;
            const u4x q = __builtin_nontemporal_load(reinterpret_cast<const u4x*>(
                U + (((size_t)r * CN + c) * ON + lane) * 4));
            float u[BN];
            u[0] = lo_bf16(q.x); u[1] = hi_bf16(q.x);
            u[2] = lo_bf16(q.y); u[3] = hi_bf16(q.y);
            u[4] = lo_bf16(q.z); u[5] = hi_bf16(q.z);
            u[6] = lo_bf16(q.w); u[7] = hi_bf16(q.w);

            float p = 0.f;
            #pragma unroll
            for (int b = 0; b < BN; ++b) p += u[b] * vreg[b];
            #pragma unroll
            for (int off = 32; off > 0; off >>= 1) p += __shfl_xor(p, off, 64);

            float bn = p * (1.0f / BN);
            if (MODE == 2) bn += bin[(size_t)r * CN + c];
            if (MODE == 1 && lane == 0) bout[(size_t)r * CN + c] = bn;
            const float e = __expf(bn);
            zacc += e;
            #pragma unroll
            for (int b = 0; b < BN; ++b) acc[b] += e * u[b];
        }
        float* sp = Sp + (size_t)chunk * SOUT;
        #pragma unroll
        for (int b = 0; b < BN; ++b)
            sp[(b * CN + c) * ON + lane] = acc[b];
        if (lane == 0)
            Zp[chunk * 32 + c] = zacc;
    }
}

// ============================================================================
// Phase: finalize — s = sum_chunks Sp, z inline from Zp (PASS>=1) or RN,
// squash, write v/out. wu = b*CN + c.
// ============================================================================
template<int PASS>
__device__ __forceinline__ void phase_fin(
    const float* __restrict__ Sp, const float* __restrict__ Zp,
    float* __restrict__ vout, SMem& sm, int nb, int bid)
{
    const int t = threadIdx.x, lane = t & 63, g = t >> 6;
    for (int wu = bid; wu < NFIN; wu += nb) {
        const int c = wu % CN;
        float z = (float)RN;
        if (PASS >= 1) {
            float zp = 0.f;
            for (int j = lane; j < NRC; j += 64) zp += Zp[j * 32 + c];
            #pragma unroll
            for (int off = 32; off > 0; off >>= 1) zp += __shfl_xor(zp, off, 64);
            z = zp;
        }
        const int base = wu * ON + lane;
        float s = 0.f;
        for (int ch = g * 40; ch < g * 40 + 40; ++ch)
            s += Sp[(size_t)ch * SOUT + base];
        __syncthreads();
        sm.red[t] = s;
        __syncthreads();
        if (g == 0) {
            float ss = sm.red[lane] + sm.red[64 + lane] + sm.red[128 + lane]
                     + sm.red[192 + lane] + sm.red[256 + lane];
            ss /= z;
            vout[base] = ss * fabsf(ss) / (1.f + ss * ss);
        }
    }
}

// ============================================================================
// Fused cooperative kernel: 6 phases, 5 grid syncs.
// ============================================================================
__global__ void __launch_bounds__(320)
caps_fused(const float* __restrict__ x, const float* __restrict__ W,
           float* __restrict__ out, float* __restrict__ v, float* __restrict__ b1,
           float* __restrict__ Zp, float* __restrict__ Sp, uint32_t* __restrict__ U)
{
    __shared__ SMem sm;
    cg::grid_group grid = cg::this_grid();
    const int nb = gridDim.x, bid = blockIdx.x;

    phase_pass0(x, W, Sp, U, sm, nb, bid);
    grid.sync();
    phase_fin<0>(Sp, Zp, v, sm, nb, bid);
    grid.sync();
    phase_passU<1>(U, v, nullptr, b1, Sp, Zp, nb, bid);
    grid.sync();
    phase_fin<1>(Sp, Zp, v, sm, nb, bid);
    grid.sync();
    phase_passU<2>(U, v, b1, nullptr, Sp, Zp, nb, bid);
    grid.sync();
    phase_fin<2>(Sp, Zp, out, sm, nb, bid);
}

// ---- Fallback non-cooperative kernels (identical math) ----
__global__ void __launch_bounds__(320)
k_pass0(const float* __restrict__ x, const float* __restrict__ W,
        float* __restrict__ Sp, uint32_t* __restrict__ U)
{
    __shared__ SMem sm;
    phase_pass0(x, W, Sp, U, sm, gridDim.x, blockIdx.x);
}
template<int MODE>
__global__ void __launch_bounds__(320)
k_passU(const uint32_t* __restrict__ U, const float* __restrict__ vin,
        const float* __restrict__ bin, float* __restrict__ bout,
        float* __restrict__ Sp, float* __restrict__ Zp)
{
    phase_passU<MODE>(U, vin, bin, bout, Sp, Zp, gridDim.x, blockIdx.x);
}
template<int PASS>
__global__ void __launch_bounds__(320)
k_fin(const float* __restrict__ Sp, const float* __restrict__ Zp,
      float* __restrict__ vout)
{
    __shared__ SMem sm;
    phase_fin<PASS>(Sp, Zp, vout, sm, gridDim.x, blockIdx.x);
}

extern "C" void kernel_launch(void* const* d_in, const int* in_sizes, int n_in,
                              void* d_out, int out_size, void* d_ws, size_t ws_size,
                              hipStream_t stream)
{
    const float* x = (const float*)d_in[0];   // [B, R, I]
    const float* W = (const float*)d_in[1];   // [R, C, O, I]
    float* out = (float*)d_out;               // [B, C, O, 1] flat = 12800
    float* ws = (float*)d_ws;

    // Workspace (floats): v[SOUT] | b1[RN*CN] | Zp[NRC*32] | Sp[NRC*SOUT] | U (uint4-aligned)
    float* v  = ws;
    float* b1 = v + SOUT;
    float* Zp = b1 + (size_t)RN * CN;
    float* Sp = Zp + (size_t)NRC * 32;
    uint32_t* U = (uint32_t*)(Sp + (size_t)NRC * SOUT);   // 327.7 MB bf16 u_hat

    // Size cooperative grid to guaranteed co-residency.
    int occ = 0;
    hipError_t err = hipOccupancyMaxActiveBlocksPerMultiprocessor(
        &occ, reinterpret_cast<const void*>(&caps_fused), 320, 0);
    bool coop = (err == hipSuccess && occ >= 1);
    int grid = occ * 256;
    if (grid > NWU) grid = NWU;

    if (coop) {
        void* args[8] = { (void*)&x, (void*)&W, (void*)&out, (void*)&v,
                          (void*)&b1, (void*)&Zp, (void*)&Sp, (void*)&U };
        err = hipLaunchCooperativeKernel(reinterpret_cast<const void*>(&caps_fused),
                                         dim3(grid), dim3(320), args, 0, stream);
        coop = (err == hipSuccess);
    }
    if (!coop) {
        dim3 blk(320), pg(NWU), fg(NFIN);
        k_pass0<<<pg, blk, 0, stream>>>(x, W, Sp, U);
        k_fin<0><<<fg, blk, 0, stream>>>(Sp, Zp, v);
        k_passU<1><<<pg, blk, 0, stream>>>(U, v, nullptr, b1, Sp, Zp);
        k_fin<1><<<fg, blk, 0, stream>>>(Sp, Zp, v);
        k_passU<2><<<pg, blk, 0, stream>>>(U, v, b1, nullptr, Sp, Zp);
        k_fin<2><<<fg, blk, 0, stream>>>(Sp, Zp, out);
    }
}

// Round 5
// 423.211 us; speedup vs baseline: 1.6117x; 1.6117x over previous
//
#include <hip/hip_runtime.h>
#include <cstdint>
#include <cstddef>

// Problem constants
#define RN 12800   // routes
#define CN 25      // caps
#define ON 64      // out channels
#define IN_ 8      // in channels
#define BN 8       // batch
#define SOUT (BN*CN*ON)   // 12800 output elems

#define RPC 64            // routes per chunk
#define NRC (RN / RPC)    // 200 chunks

// ---- bf16 helpers (RNE) ----
__device__ __forceinline__ uint32_t pack_bf16(float a, float b) {
    uint32_t ua = __float_as_uint(a);
    uint32_t ub = __float_as_uint(b);
    ua = (ua + 0x7fffu + ((ua >> 16) & 1u)) >> 16;          // bf16(a) low half
    ub = (ub + 0x7fffu + ((ub >> 16) & 1u)) & 0xffff0000u;  // bf16(b) high half
    return ua | ub;
}
__device__ __forceinline__ float lo_bf16(uint32_t q) { return __uint_as_float(q << 16); }
__device__ __forceinline__ float hi_bf16(uint32_t q) { return __uint_as_float(q & 0xffff0000u); }

__device__ __forceinline__ float squashf(float s) {
    return s * fabsf(s) / (1.f + s * s);
}

// ============================================================================
// kzero: zero S0|S1|S2|za|zb (3*SOUT + 64 floats). Runs first every launch —
// also covers the harness's 0xAA poison of d_ws before timed replays.
// ============================================================================
#define NZERO (3 * SOUT + 64)
__global__ void kzero(float* __restrict__ p)
{
    const int i = blockIdx.x * blockDim.x + threadIdx.x;
    if (i < NZERO) p[i] = 0.f;
}

// ============================================================================
// pass0: u = W·x per (b,r,c,o); store u as bf16; atomic-accumulate S0 = sum_r u.
// block = 320 thr = 5 waves; wave w owns c = blockIdx.x*5 + w; lane = o.
// grid = (5, NRC); chunk = blockIdx.y.
// ============================================================================
__global__ void __launch_bounds__(320, 6)
caps_pass0(const float* __restrict__ x, const float* __restrict__ W,
           float* __restrict__ S0, uint32_t* __restrict__ U)
{
    __shared__ float xs[RPC][BN][IN_];   // 16 KB
    const int chunk = blockIdx.y;
    const int r0 = chunk * RPC;

    for (int t = threadIdx.x; t < RPC * BN * 2; t += 320) {
        const int i4 = t & 1;
        const int rl = (t >> 1) & (RPC - 1);
        const int b  = t >> 7;
        const float4 val = *reinterpret_cast<const float4*>(
            x + (((size_t)b * RN + r0 + rl) * IN_) + i4 * 4);
        *reinterpret_cast<float4*>(&xs[rl][b][i4 * 4]) = val;
    }
    __syncthreads();

    const int wave = threadIdx.x >> 6;
    const int lane = threadIdx.x & 63;
    const int c = blockIdx.x * 5 + wave;

    float acc[BN];
    #pragma unroll
    for (int b = 0; b < BN; ++b) acc[b] = 0.f;

    #pragma unroll 2
    for (int rl = 0; rl < RPC; ++rl) {
        const int r = r0 + rl;
        const float4* wp = reinterpret_cast<const float4*>(
            W + ((((size_t)r * CN + c) * ON + lane) * IN_));
        const float4 w0 = wp[0];
        const float4 w1 = wp[1];

        float u[BN];
        #pragma unroll
        for (int b = 0; b < BN; ++b) {
            const float4 xa = *reinterpret_cast<const float4*>(&xs[rl][b][0]);
            const float4 xb = *reinterpret_cast<const float4*>(&xs[rl][b][4]);
            u[b] = w0.x*xa.x + w0.y*xa.y + w0.z*xa.z + w0.w*xa.w
                 + w1.x*xb.x + w1.y*xb.y + w1.z*xb.z + w1.w*xb.w;
            acc[b] += u[b];
        }
        uint4 q;
        q.x = pack_bf16(u[0], u[1]);
        q.y = pack_bf16(u[2], u[3]);
        q.z = pack_bf16(u[4], u[5]);
        q.w = pack_bf16(u[6], u[7]);
        *reinterpret_cast<uint4*>(U + (((size_t)r * CN + c) * ON + lane) * 4) = q;
    }

    #pragma unroll
    for (int b = 0; b < BN; ++b)
        unsafeAtomicAdd(&S0[(b * CN + c) * ON + lane], acc[b]);
}

// ============================================================================
// passU<MODE>: reads bf16 u_hat only. Prologue recomputes v from (Sprev, zprev)
// for this block's capsule (L2-hot, 8 coalesced loads). MODE 1: z = RN,
// b1 = mean_b<u,v0> stored. MODE 2: z = zprev[c], b2 = b1 + mean_b<u,v1>.
// Accumulates Snext, znext via atomics.
// ============================================================================
template<int MODE>
__global__ void __launch_bounds__(320, 6)
caps_passU(const uint32_t* __restrict__ U,
           const float* __restrict__ Sprev, const float* __restrict__ zprev,
           float* __restrict__ Snext, float* __restrict__ znext,
           float* __restrict__ b1)
{
    const int chunk = blockIdx.y;
    const int r0 = chunk * RPC;
    const int wave = threadIdx.x >> 6;
    const int lane = threadIdx.x & 63;
    const int c = blockIdx.x * 5 + wave;

    const float zz = (MODE == 1) ? (float)RN : zprev[c];
    float vreg[BN];
    #pragma unroll
    for (int b = 0; b < BN; ++b) {
        const float sv = Sprev[(b * CN + c) * ON + lane] / zz;
        vreg[b] = squashf(sv);
    }

    float acc[BN];
    #pragma unroll
    for (int b = 0; b < BN; ++b) acc[b] = 0.f;
    float zacc = 0.f;

    #pragma unroll 2
    for (int rl = 0; rl < RPC; ++rl) {
        const int r = r0 + rl;
        const uint4 q = *reinterpret_cast<const uint4*>(
            U + (((size_t)r * CN + c) * ON + lane) * 4);
        float u[BN];
        u[0] = lo_bf16(q.x); u[1] = hi_bf16(q.x);
        u[2] = lo_bf16(q.y); u[3] = hi_bf16(q.y);
        u[4] = lo_bf16(q.z); u[5] = hi_bf16(q.z);
        u[6] = lo_bf16(q.w); u[7] = hi_bf16(q.w);

        float p = 0.f;
        #pragma unroll
        for (int b = 0; b < BN; ++b) p += u[b] * vreg[b];
        // sum over 64 lanes (= sum over o); butterfly, result in all lanes
        #pragma unroll
        for (int off = 32; off > 0; off >>= 1) p += __shfl_xor(p, off, 64);

        float bn = p * (1.0f / BN);
        if (MODE == 2) bn += b1[(size_t)r * CN + c];
        if (MODE == 1 && lane == 0) b1[(size_t)r * CN + c] = bn;
        const float e = __expf(bn);
        zacc += e;
        #pragma unroll
        for (int b = 0; b < BN; ++b) acc[b] += e * u[b];
    }

    #pragma unroll
    for (int b = 0; b < BN; ++b)
        unsafeAtomicAdd(&Snext[(b * CN + c) * ON + lane], acc[b]);
    if (lane == 0)
        unsafeAtomicAdd(&znext[c], zacc);   // e is wave-uniform; zacc identical per lane
}

// ============================================================================
// sqfin: out = squash(S2 / zb[c])
// ============================================================================
__global__ void caps_sqfin(const float* __restrict__ S2, const float* __restrict__ zb,
                           float* __restrict__ out)
{
    const int idx = blockIdx.x * blockDim.x + threadIdx.x;
    if (idx >= SOUT) return;
    const int c = (idx >> 6) % CN;
    const float s = S2[idx] / zb[c];
    out[idx] = squashf(s);
}

extern "C" void kernel_launch(void* const* d_in, const int* in_sizes, int n_in,
                              void* d_out, int out_size, void* d_ws, size_t ws_size,
                              hipStream_t stream)
{
    const float* x = (const float*)d_in[0];   // [B, R, I]
    const float* W = (const float*)d_in[1];   // [R, C, O, I]
    float* out = (float*)d_out;               // [B, C, O, 1] flat = 12800
    float* ws = (float*)d_ws;

    // Workspace (floats): S0[SOUT] S1[SOUT] S2[SOUT] za[32] zb[32] | b1[RN*CN] | U
    float* S0 = ws;
    float* S1 = S0 + SOUT;
    float* S2 = S1 + SOUT;
    float* za = S2 + SOUT;
    float* zb = za + 32;
    float* b1 = zb + 32;
    uint32_t* U = (uint32_t*)(b1 + (size_t)RN * CN);   // 327.7 MB bf16 u_hat, 16B-aligned

    dim3 blk(320), grid(5, NRC);

    kzero<<<(NZERO + 255) / 256, 256, 0, stream>>>(S0);
    // it 0: u = W·x (store bf16), S0 = sum_r u (atomic)
    caps_pass0<<<grid, blk, 0, stream>>>(x, W, S0, U);
    // it 1: v0 = squash(S0/RN) in-prologue; b1 = mean_b<u,v0>; S1,za (atomic)
    caps_passU<1><<<grid, blk, 0, stream>>>(U, S0, nullptr, S1, za, b1);
    // it 2: v1 = squash(S1/za) in-prologue; b2 = b1 + mean_b<u,v1>; S2,zb (atomic)
    caps_passU<2><<<grid, blk, 0, stream>>>(U, S1, za, S2, zb, b1);
    // final: out = squash(S2/zb)
    caps_sqfin<<<(SOUT + 255) / 256, 256, 0, stream>>>(S2, zb, out);
}

// Round 6
// 363.713 us; speedup vs baseline: 1.8754x; 1.1636x over previous
//
#include <hip/hip_runtime.h>
#include <cstdint>
#include <cstddef>

// Problem constants
#define RN 12800   // routes
#define CN 25      // caps
#define ON 64      // out channels
#define IN_ 8      // in channels
#define BN 8       // batch
#define SOUT (BN*CN*ON)   // 12800 output elems

#define RPC 64            // routes per chunk
#define NRC (RN / RPC)    // 200 chunks
#define NFIN (BN * CN)    // 200 finalize blocks

typedef float    f4x __attribute__((ext_vector_type(4)));
typedef uint32_t u4x __attribute__((ext_vector_type(4)));

// ---- bf16 helpers (RNE) ----
__device__ __forceinline__ uint32_t pack_bf16(float a, float b) {
    uint32_t ua = __float_as_uint(a);
    uint32_t ub = __float_as_uint(b);
    ua = (ua + 0x7fffu + ((ua >> 16) & 1u)) >> 16;          // bf16(a) low half
    ub = (ub + 0x7fffu + ((ub >> 16) & 1u)) & 0xffff0000u;  // bf16(b) high half
    return ua | ub;
}
__device__ __forceinline__ float lo_bf16(uint32_t q) { return __uint_as_float(q << 16); }
__device__ __forceinline__ float hi_bf16(uint32_t q) { return __uint_as_float(q & 0xffff0000u); }
__device__ __forceinline__ float squashf(float s) { return s * fabsf(s) / (1.f + s * s); }

// ============================================================================
// pass0: u = W·x per (b,r,c,o); store u bf16 (regular store -> L3-allocate);
// W loads NONTEMPORAL (streamed once, keep L3 for U). Sp[chunk] partials.
// block = 320 thr = 5 waves; wave w owns c = blockIdx.x*5 + w; lane = o.
// ============================================================================
__global__ void __launch_bounds__(320, 6)
caps_pass0(const float* __restrict__ x, const float* __restrict__ W,
           float* __restrict__ Sp, uint32_t* __restrict__ U)
{
    __shared__ float xs[RPC][BN][IN_];   // 16 KB
    const int chunk = blockIdx.y;
    const int r0 = chunk * RPC;

    for (int t = threadIdx.x; t < RPC * BN * 2; t += 320) {
        const int i4 = t & 1;
        const int rl = (t >> 1) & (RPC - 1);
        const int b  = t >> 7;
        const float4 val = *reinterpret_cast<const float4*>(
            x + (((size_t)b * RN + r0 + rl) * IN_) + i4 * 4);
        *reinterpret_cast<float4*>(&xs[rl][b][i4 * 4]) = val;
    }
    __syncthreads();

    const int wave = threadIdx.x >> 6;
    const int lane = threadIdx.x & 63;
    const int c = blockIdx.x * 5 + wave;

    float acc[BN];
    #pragma unroll
    for (int b = 0; b < BN; ++b) acc[b] = 0.f;

    #pragma unroll 2
    for (int rl = 0; rl < RPC; ++rl) {
        const int r = r0 + rl;
        const f4x* wp = reinterpret_cast<const f4x*>(
            W + ((((size_t)r * CN + c) * ON + lane) * IN_));
        const f4x w0 = __builtin_nontemporal_load(wp);
        const f4x w1 = __builtin_nontemporal_load(wp + 1);

        float u[BN];
        #pragma unroll
        for (int b = 0; b < BN; ++b) {
            const float4 xa = *reinterpret_cast<const float4*>(&xs[rl][b][0]);
            const float4 xb = *reinterpret_cast<const float4*>(&xs[rl][b][4]);
            u[b] = w0.x*xa.x + w0.y*xa.y + w0.z*xa.z + w0.w*xa.w
                 + w1.x*xb.x + w1.y*xb.y + w1.z*xb.z + w1.w*xb.w;
            acc[b] += u[b];
        }
        uint4 q;
        q.x = pack_bf16(u[0], u[1]);
        q.y = pack_bf16(u[2], u[3]);
        q.z = pack_bf16(u[4], u[5]);
        q.w = pack_bf16(u[6], u[7]);
        *reinterpret_cast<uint4*>(U + (((size_t)r * CN + c) * ON + lane) * 4) = q;
    }

    float* sp = Sp + (size_t)chunk * SOUT;
    #pragma unroll
    for (int b = 0; b < BN; ++b)
        sp[(b * CN + c) * ON + lane] = acc[b];
}

// ============================================================================
// passU<MODE>: read bf16 u_hat only. MODE 1: regular U loads (U re-read by
// pass 2 — keep resident); b1 = mean_b<u,v0> stored. MODE 2: NONTEMPORAL U
// loads (last use); b2 = b1 + mean_b<u,v1>. Sp/Zp partials per chunk.
// ============================================================================
template<int MODE>
__global__ void __launch_bounds__(320, 6)
caps_passU(const uint32_t* __restrict__ U, const float* __restrict__ vin,
           const float* __restrict__ bin, float* __restrict__ bout,
           float* __restrict__ Sp, float* __restrict__ Zp)
{
    const int chunk = blockIdx.y;
    const int r0 = chunk * RPC;
    const int wave = threadIdx.x >> 6;
    const int lane = threadIdx.x & 63;
    const int c = blockIdx.x * 5 + wave;

    float vreg[BN];
    #pragma unroll
    for (int b = 0; b < BN; ++b)
        vreg[b] = vin[(b * CN + c) * ON + lane];

    float acc[BN];
    #pragma unroll
    for (int b = 0; b < BN; ++b) acc[b] = 0.f;
    float zacc = 0.f;

    #pragma unroll 2
    for (int rl = 0; rl < RPC; ++rl) {
        const int r = r0 + rl;
        const u4x* up = reinterpret_cast<const u4x*>(
            U + (((size_t)r * CN + c) * ON + lane) * 4);
        const u4x q = (MODE == 2) ? __builtin_nontemporal_load(up) : *up;
        float u[BN];
        u[0] = lo_bf16(q.x); u[1] = hi_bf16(q.x);
        u[2] = lo_bf16(q.y); u[3] = hi_bf16(q.y);
        u[4] = lo_bf16(q.z); u[5] = hi_bf16(q.z);
        u[6] = lo_bf16(q.w); u[7] = hi_bf16(q.w);

        float p = 0.f;
        #pragma unroll
        for (int b = 0; b < BN; ++b) p += u[b] * vreg[b];
        // sum over 64 lanes (= sum over o); butterfly, result in all lanes
        #pragma unroll
        for (int off = 32; off > 0; off >>= 1) p += __shfl_xor(p, off, 64);

        float bn = p * (1.0f / BN);
        if (MODE == 2) bn += bin[(size_t)r * CN + c];
        if (MODE == 1 && lane == 0) bout[(size_t)r * CN + c] = bn;
        const float e = __expf(bn);
        zacc += e;
        #pragma unroll
        for (int b = 0; b < BN; ++b) acc[b] += e * u[b];
    }

    float* sp = Sp + (size_t)chunk * SOUT;
    #pragma unroll
    for (int b = 0; b < BN; ++b)
        sp[(b * CN + c) * ON + lane] = acc[b];
    if (lane == 0)
        Zp[chunk * 32 + c] = zacc;
}

// ============================================================================
// fin<PASS>: one block per (b,c); z inline from Zp (lane-parallel) or RN;
// 5 groups of 64 lanes each sum 40 chunks of Sp; LDS reduce; squash; write.
// ============================================================================
template<int PASS>
__global__ void __launch_bounds__(320)
caps_fin(const float* __restrict__ Sp, const float* __restrict__ Zp,
         float* __restrict__ vout)
{
    __shared__ float red[320];
    const int wu = blockIdx.x;           // b*CN + c
    const int t = threadIdx.x, lane = t & 63, g = t >> 6;
    const int c = wu % CN;

    float z = (float)RN;
    if (PASS >= 1) {
        float zp = 0.f;
        for (int j = lane; j < NRC; j += 64) zp += Zp[j * 32 + c];
        #pragma unroll
        for (int off = 32; off > 0; off >>= 1) zp += __shfl_xor(zp, off, 64);
        z = zp;
    }
    const int base = wu * ON + lane;
    float s = 0.f;
    for (int ch = g * 40; ch < g * 40 + 40; ++ch)
        s += Sp[(size_t)ch * SOUT + base];
    red[t] = s;
    __syncthreads();
    if (g == 0) {
        float ss = red[lane] + red[64 + lane] + red[128 + lane]
                 + red[192 + lane] + red[256 + lane];
        ss /= z;
        vout[base] = squashf(ss);
    }
}

extern "C" void kernel_launch(void* const* d_in, const int* in_sizes, int n_in,
                              void* d_out, int out_size, void* d_ws, size_t ws_size,
                              hipStream_t stream)
{
    const float* x = (const float*)d_in[0];   // [B, R, I]
    const float* W = (const float*)d_in[1];   // [R, C, O, I]
    float* out = (float*)d_out;               // [B, C, O, 1] flat = 12800
    float* ws = (float*)d_ws;

    // Workspace (floats): v[SOUT] | b1[RN*CN] | Zp[NRC*32] | Sp[NRC*SOUT] | U
    float* v  = ws;
    float* b1 = v + SOUT;
    float* Zp = b1 + (size_t)RN * CN;
    float* Sp = Zp + (size_t)NRC * 32;
    uint32_t* U = (uint32_t*)(Sp + (size_t)NRC * SOUT);   // 327.7 MB bf16 u_hat

    dim3 blk(320), grid(5, NRC), fg(NFIN);

    // it 0: u = W·x (store bf16), S0 partials; v0 = squash(S0/RN)
    caps_pass0<<<grid, blk, 0, stream>>>(x, W, Sp, U);
    caps_fin<0><<<fg, blk, 0, stream>>>(Sp, Zp, v);
    // it 1: b1 = mean_b<u,v0> (store); S1,Z1 partials; v1 = squash(S1/z1)
    caps_passU<1><<<grid, blk, 0, stream>>>(U, v, nullptr, b1, Sp, Zp);
    caps_fin<1><<<fg, blk, 0, stream>>>(Sp, Zp, v);
    // it 2: b2 = b1 + mean_b<u,v1>; S2,Z2 partials; out = squash(S2/z2)
    caps_passU<2><<<grid, blk, 0, stream>>>(U, v, b1, nullptr, Sp, Zp);
    caps_fin<2><<<fg, blk, 0, stream>>>(Sp, Zp, out);
}

// Round 7
// 361.222 us; speedup vs baseline: 1.8883x; 1.0069x over previous
//
#include <hip/hip_runtime.h>
#include <cstdint>
#include <cstddef>

// Problem constants
#define RN 12800   // routes
#define CN 25      // caps
#define ON 64      // out channels
#define IN_ 8      // in channels
#define BN 8       // batch
#define SOUT (BN*CN*ON)   // 12800 output elems

#define RPC 64            // routes per chunk
#define NRC (RN / RPC)    // 200 chunks
#define NFIN (BN * CN)    // 200 finalize blocks

typedef float    f4x __attribute__((ext_vector_type(4)));
typedef uint32_t u4x __attribute__((ext_vector_type(4)));

// ---- bf16 helpers (RNE) ----
__device__ __forceinline__ uint32_t pack_bf16(float a, float b) {
    uint32_t ua = __float_as_uint(a);
    uint32_t ub = __float_as_uint(b);
    ua = (ua + 0x7fffu + ((ua >> 16) & 1u)) >> 16;          // bf16(a) low half
    ub = (ub + 0x7fffu + ((ub >> 16) & 1u)) & 0xffff0000u;  // bf16(b) high half
    return ua | ub;
}
__device__ __forceinline__ float lo_bf16(uint32_t q) { return __uint_as_float(q << 16); }
__device__ __forceinline__ float hi_bf16(uint32_t q) { return __uint_as_float(q & 0xffff0000u); }
__device__ __forceinline__ float squashf(float s) { return s * fabsf(s) / (1.f + s * s); }

// ============================================================================
// pass0: u = W·x per (b,r,c,o); store u bf16 (regular store -> L3 allocates,
// chunk order ascending in time); W loads NONTEMPORAL (streamed once, keep
// L3 for U). Sp[chunk] partials. block = 320 thr = 5 waves; wave w owns
// c = blockIdx.x*5 + w; lane = o.
// ============================================================================
__global__ void __launch_bounds__(320, 6)
caps_pass0(const float* __restrict__ x, const float* __restrict__ W,
           float* __restrict__ Sp, uint32_t* __restrict__ U)
{
    __shared__ float xs[RPC][BN][IN_];   // 16 KB
    const int chunk = blockIdx.y;
    const int r0 = chunk * RPC;

    for (int t = threadIdx.x; t < RPC * BN * 2; t += 320) {
        const int i4 = t & 1;
        const int rl = (t >> 1) & (RPC - 1);
        const int b  = t >> 7;
        const float4 val = *reinterpret_cast<const float4*>(
            x + (((size_t)b * RN + r0 + rl) * IN_) + i4 * 4);
        *reinterpret_cast<float4*>(&xs[rl][b][i4 * 4]) = val;
    }
    __syncthreads();

    const int wave = threadIdx.x >> 6;
    const int lane = threadIdx.x & 63;
    const int c = blockIdx.x * 5 + wave;

    float acc[BN];
    #pragma unroll
    for (int b = 0; b < BN; ++b) acc[b] = 0.f;

    #pragma unroll 2
    for (int rl = 0; rl < RPC; ++rl) {
        const int r = r0 + rl;
        const f4x* wp = reinterpret_cast<const f4x*>(
            W + ((((size_t)r * CN + c) * ON + lane) * IN_));
        const f4x w0 = __builtin_nontemporal_load(wp);
        const f4x w1 = __builtin_nontemporal_load(wp + 1);

        float u[BN];
        #pragma unroll
        for (int b = 0; b < BN; ++b) {
            const float4 xa = *reinterpret_cast<const float4*>(&xs[rl][b][0]);
            const float4 xb = *reinterpret_cast<const float4*>(&xs[rl][b][4]);
            u[b] = w0.x*xa.x + w0.y*xa.y + w0.z*xa.z + w0.w*xa.w
                 + w1.x*xb.x + w1.y*xb.y + w1.z*xb.z + w1.w*xb.w;
            acc[b] += u[b];
        }
        uint4 q;
        q.x = pack_bf16(u[0], u[1]);
        q.y = pack_bf16(u[2], u[3]);
        q.z = pack_bf16(u[4], u[5]);
        q.w = pack_bf16(u[6], u[7]);
        *reinterpret_cast<uint4*>(U + (((size_t)r * CN + c) * ON + lane) * 4) = q;
    }

    float* sp = Sp + (size_t)chunk * SOUT;
    #pragma unroll
    for (int b = 0; b < BN; ++b)
        sp[(b * CN + c) * ON + lane] = acc[b];
}

// ============================================================================
// passU<MODE>: read bf16 u_hat only.
// MODE 1: chunk order REVERSED (199-by) so the newest-written U (still
//         L3-resident) is read first; regular loads re-allocate descending.
//         b1 = mean_b<u,v0> stored.
// MODE 2: ascending order (reads passU1's last-touched lines first),
//         NONTEMPORAL U loads (last use). b2 = b1 + mean_b<u,v1>.
// Sp/Zp partials per chunk.
// ============================================================================
template<int MODE>
__global__ void __launch_bounds__(320, 6)
caps_passU(const uint32_t* __restrict__ U, const float* __restrict__ vin,
           const float* __restrict__ bin, float* __restrict__ bout,
           float* __restrict__ Sp, float* __restrict__ Zp)
{
    const int chunk = (MODE == 1) ? (NRC - 1 - blockIdx.y) : blockIdx.y;
    const int r0 = chunk * RPC;
    const int wave = threadIdx.x >> 6;
    const int lane = threadIdx.x & 63;
    const int c = blockIdx.x * 5 + wave;

    float vreg[BN];
    #pragma unroll
    for (int b = 0; b < BN; ++b)
        vreg[b] = vin[(b * CN + c) * ON + lane];

    float acc[BN];
    #pragma unroll
    for (int b = 0; b < BN; ++b) acc[b] = 0.f;
    float zacc = 0.f;

    #pragma unroll 2
    for (int rl = 0; rl < RPC; ++rl) {
        const int r = r0 + rl;
        const u4x* up = reinterpret_cast<const u4x*>(
            U + (((size_t)r * CN + c) * ON + lane) * 4);
        const u4x q = (MODE == 2) ? __builtin_nontemporal_load(up) : *up;
        float u[BN];
        u[0] = lo_bf16(q.x); u[1] = hi_bf16(q.x);
        u[2] = lo_bf16(q.y); u[3] = hi_bf16(q.y);
        u[4] = lo_bf16(q.z); u[5] = hi_bf16(q.z);
        u[6] = lo_bf16(q.w); u[7] = hi_bf16(q.w);

        float p = 0.f;
        #pragma unroll
        for (int b = 0; b < BN; ++b) p += u[b] * vreg[b];
        // sum over 64 lanes (= sum over o); butterfly, result in all lanes
        #pragma unroll
        for (int off = 32; off > 0; off >>= 1) p += __shfl_xor(p, off, 64);

        float bn = p * (1.0f / BN);
        if (MODE == 2) bn += bin[(size_t)r * CN + c];
        if (MODE == 1 && lane == 0) bout[(size_t)r * CN + c] = bn;
        const float e = __expf(bn);
        zacc += e;
        #pragma unroll
        for (int b = 0; b < BN; ++b) acc[b] += e * u[b];
    }

    float* sp = Sp + (size_t)chunk * SOUT;
    #pragma unroll
    for (int b = 0; b < BN; ++b)
        sp[(b * CN + c) * ON + lane] = acc[b];
    if (lane == 0)
        Zp[chunk * 32 + c] = zacc;
}

// ============================================================================
// fin<PASS>: one block per (b,c); z inline from Zp (lane-parallel) or RN;
// 5 groups of 64 lanes each sum 40 chunks of Sp; LDS reduce; squash; write.
// ============================================================================
template<int PASS>
__global__ void __launch_bounds__(320)
caps_fin(const float* __restrict__ Sp, const float* __restrict__ Zp,
         float* __restrict__ vout)
{
    __shared__ float red[320];
    const int wu = blockIdx.x;           // b*CN + c
    const int t = threadIdx.x, lane = t & 63, g = t >> 6;
    const int c = wu % CN;

    float z = (float)RN;
    if (PASS >= 1) {
        float zp = 0.f;
        for (int j = lane; j < NRC; j += 64) zp += Zp[j * 32 + c];
        #pragma unroll
        for (int off = 32; off > 0; off >>= 1) zp += __shfl_xor(zp, off, 64);
        z = zp;
    }
    const int base = wu * ON + lane;
    float s = 0.f;
    for (int ch = g * 40; ch < g * 40 + 40; ++ch)
        s += Sp[(size_t)ch * SOUT + base];
    red[t] = s;
    __syncthreads();
    if (g == 0) {
        float ss = red[lane] + red[64 + lane] + red[128 + lane]
                 + red[192 + lane] + red[256 + lane];
        ss /= z;
        vout[base] = squashf(ss);
    }
}

extern "C" void kernel_launch(void* const* d_in, const int* in_sizes, int n_in,
                              void* d_out, int out_size, void* d_ws, size_t ws_size,
                              hipStream_t stream)
{
    const float* x = (const float*)d_in[0];   // [B, R, I]
    const float* W = (const float*)d_in[1];   // [R, C, O, I]
    float* out = (float*)d_out;               // [B, C, O, 1] flat = 12800
    float* ws = (float*)d_ws;

    // Workspace (floats): v[SOUT] | b1[RN*CN] | Zp[NRC*32] | Sp[NRC*SOUT] | U
    float* v  = ws;
    float* b1 = v + SOUT;
    float* Zp = b1 + (size_t)RN * CN;
    float* Sp = Zp + (size_t)NRC * 32;
    uint32_t* U = (uint32_t*)(Sp + (size_t)NRC * SOUT);   // 327.7 MB bf16 u_hat

    dim3 blk(320), grid(5, NRC), fg(NFIN);

    // it 0: u = W·x (store bf16), S0 partials; v0 = squash(S0/RN)
    caps_pass0<<<grid, blk, 0, stream>>>(x, W, Sp, U);
    caps_fin<0><<<fg, blk, 0, stream>>>(Sp, Zp, v);
    // it 1 (reversed chunk order): b1 = mean_b<u,v0>; S1,Z1 partials; v1
    caps_passU<1><<<grid, blk, 0, stream>>>(U, v, nullptr, b1, Sp, Zp);
    caps_fin<1><<<fg, blk, 0, stream>>>(Sp, Zp, v);
    // it 2 (ascending, nt): b2 = b1 + mean_b<u,v1>; S2,Z2 partials; out
    caps_passU<2><<<grid, blk, 0, stream>>>(U, v, b1, nullptr, Sp, Zp);
    caps_fin<2><<<fg, blk, 0, stream>>>(Sp, Zp, out);
}

// Round 8
// 360.331 us; speedup vs baseline: 1.8930x; 1.0025x over previous
//
#include <hip/hip_runtime.h>
#include <cstdint>
#include <cstddef>

// Problem constants
#define RN 12800   // routes
#define CN 25      // caps
#define ON 64      // out channels
#define IN_ 8      // in channels
#define BN 8       // batch
#define SOUT (BN*CN*ON)   // 12800 output elems

#define RPC 64            // routes per chunk
#define NRC (RN / RPC)    // 200 chunks
#define NFIN (BN * CN)    // 200 finalize blocks

typedef float    f4x __attribute__((ext_vector_type(4)));
typedef uint32_t u4x __attribute__((ext_vector_type(4)));

// ---- bf16 helpers (RNE) ----
__device__ __forceinline__ uint32_t pack_bf16(float a, float b) {
    uint32_t ua = __float_as_uint(a);
    uint32_t ub = __float_as_uint(b);
    ua = (ua + 0x7fffu + ((ua >> 16) & 1u)) >> 16;          // bf16(a) low half
    ub = (ub + 0x7fffu + ((ub >> 16) & 1u)) & 0xffff0000u;  // bf16(b) high half
    return ua | ub;
}
__device__ __forceinline__ float lo_bf16(uint32_t q) { return __uint_as_float(q << 16); }
__device__ __forceinline__ float hi_bf16(uint32_t q) { return __uint_as_float(q & 0xffff0000u); }
__device__ __forceinline__ float squashf(float s) { return s * fabsf(s) / (1.f + s * s); }

// ============================================================================
// pass0: u = W·x per (b,r,c,o); U stored bf16 NONTEMPORAL (no reuse until a
// later kernel; don't churn L2); W loads NONTEMPORAL (streamed once).
// Sp[chunk] partials regular (read by fin within µs). block = 320 thr =
// 5 waves; wave w owns c = blockIdx.x*5 + w; lane = o.
// ============================================================================
__global__ void __launch_bounds__(320, 6)
caps_pass0(const float* __restrict__ x, const float* __restrict__ W,
           float* __restrict__ Sp, uint32_t* __restrict__ U)
{
    __shared__ float xs[RPC][BN][IN_];   // 16 KB
    const int chunk = blockIdx.y;
    const int r0 = chunk * RPC;

    for (int t = threadIdx.x; t < RPC * BN * 2; t += 320) {
        const int i4 = t & 1;
        const int rl = (t >> 1) & (RPC - 1);
        const int b  = t >> 7;
        const float4 val = *reinterpret_cast<const float4*>(
            x + (((size_t)b * RN + r0 + rl) * IN_) + i4 * 4);
        *reinterpret_cast<float4*>(&xs[rl][b][i4 * 4]) = val;
    }
    __syncthreads();

    const int wave = threadIdx.x >> 6;
    const int lane = threadIdx.x & 63;
    const int c = blockIdx.x * 5 + wave;

    float acc[BN];
    #pragma unroll
    for (int b = 0; b < BN; ++b) acc[b] = 0.f;

    #pragma unroll 2
    for (int rl = 0; rl < RPC; ++rl) {
        const int r = r0 + rl;
        const f4x* wp = reinterpret_cast<const f4x*>(
            W + ((((size_t)r * CN + c) * ON + lane) * IN_));
        const f4x w0 = __builtin_nontemporal_load(wp);
        const f4x w1 = __builtin_nontemporal_load(wp + 1);

        float u[BN];
        #pragma unroll
        for (int b = 0; b < BN; ++b) {
            const float4 xa = *reinterpret_cast<const float4*>(&xs[rl][b][0]);
            const float4 xb = *reinterpret_cast<const float4*>(&xs[rl][b][4]);
            u[b] = w0.x*xa.x + w0.y*xa.y + w0.z*xa.z + w0.w*xa.w
                 + w1.x*xb.x + w1.y*xb.y + w1.z*xb.z + w1.w*xb.w;
            acc[b] += u[b];
        }
        u4x q;
        q.x = pack_bf16(u[0], u[1]);
        q.y = pack_bf16(u[2], u[3]);
        q.z = pack_bf16(u[4], u[5]);
        q.w = pack_bf16(u[6], u[7]);
        __builtin_nontemporal_store(q, reinterpret_cast<u4x*>(
            U + (((size_t)r * CN + c) * ON + lane) * 4));
    }

    float* sp = Sp + (size_t)chunk * SOUT;
    #pragma unroll
    for (int b = 0; b < BN; ++b)
        sp[(b * CN + c) * ON + lane] = acc[b];
}

// ============================================================================
// passU<MODE>: read bf16 u_hat only (NONTEMPORAL — no cross-kernel retention,
// measured R7). MODE 1: b1 = mean_b<u,v0> stored. MODE 2: b2 = b1(load) +
// mean_b<u,v1>. Sp/Zp partials per chunk (regular stores, fin reads soon).
// ============================================================================
template<int MODE>
__global__ void __launch_bounds__(320, 6)
caps_passU(const uint32_t* __restrict__ U, const float* __restrict__ vin,
           const float* __restrict__ bin, float* __restrict__ bout,
           float* __restrict__ Sp, float* __restrict__ Zp)
{
    const int chunk = blockIdx.y;
    const int r0 = chunk * RPC;
    const int wave = threadIdx.x >> 6;
    const int lane = threadIdx.x & 63;
    const int c = blockIdx.x * 5 + wave;

    float vreg[BN];
    #pragma unroll
    for (int b = 0; b < BN; ++b)
        vreg[b] = vin[(b * CN + c) * ON + lane];

    float acc[BN];
    #pragma unroll
    for (int b = 0; b < BN; ++b) acc[b] = 0.f;
    float zacc = 0.f;

    #pragma unroll 2
    for (int rl = 0; rl < RPC; ++rl) {
        const int r = r0 + rl;
        const u4x q = __builtin_nontemporal_load(reinterpret_cast<const u4x*>(
            U + (((size_t)r * CN + c) * ON + lane) * 4));
        float u[BN];
        u[0] = lo_bf16(q.x); u[1] = hi_bf16(q.x);
        u[2] = lo_bf16(q.y); u[3] = hi_bf16(q.y);
        u[4] = lo_bf16(q.z); u[5] = hi_bf16(q.z);
        u[6] = lo_bf16(q.w); u[7] = hi_bf16(q.w);

        float p = 0.f;
        #pragma unroll
        for (int b = 0; b < BN; ++b) p += u[b] * vreg[b];
        // sum over 64 lanes (= sum over o); butterfly, result in all lanes
        #pragma unroll
        for (int off = 32; off > 0; off >>= 1) p += __shfl_xor(p, off, 64);

        float bn = p * (1.0f / BN);
        if (MODE == 2) bn += bin[(size_t)r * CN + c];
        if (MODE == 1 && lane == 0) bout[(size_t)r * CN + c] = bn;
        const float e = __expf(bn);
        zacc += e;
        #pragma unroll
        for (int b = 0; b < BN; ++b) acc[b] += e * u[b];
    }

    float* sp = Sp + (size_t)chunk * SOUT;
    #pragma unroll
    for (int b = 0; b < BN; ++b)
        sp[(b * CN + c) * ON + lane] = acc[b];
    if (lane == 0)
        Zp[chunk * 32 + c] = zacc;
}

// ============================================================================
// fin<PASS>: one block per (b,c); z inline from Zp (lane-parallel) or RN;
// 5 groups of 64 lanes each sum 40 chunks of Sp; LDS reduce; squash; write.
// ============================================================================
template<int PASS>
__global__ void __launch_bounds__(320)
caps_fin(const float* __restrict__ Sp, const float* __restrict__ Zp,
         float* __restrict__ vout)
{
    __shared__ float red[320];
    const int wu = blockIdx.x;           // b*CN + c
    const int t = threadIdx.x, lane = t & 63, g = t >> 6;
    const int c = wu % CN;

    float z = (float)RN;
    if (PASS >= 1) {
        float zp = 0.f;
        for (int j = lane; j < NRC; j += 64) zp += Zp[j * 32 + c];
        #pragma unroll
        for (int off = 32; off > 0; off >>= 1) zp += __shfl_xor(zp, off, 64);
        z = zp;
    }
    const int base = wu * ON + lane;
    float s = 0.f;
    for (int ch = g * 40; ch < g * 40 + 40; ++ch)
        s += Sp[(size_t)ch * SOUT + base];
    red[t] = s;
    __syncthreads();
    if (g == 0) {
        float ss = red[lane] + red[64 + lane] + red[128 + lane]
                 + red[192 + lane] + red[256 + lane];
        ss /= z;
        vout[base] = squashf(ss);
    }
}

extern "C" void kernel_launch(void* const* d_in, const int* in_sizes, int n_in,
                              void* d_out, int out_size, void* d_ws, size_t ws_size,
                              hipStream_t stream)
{
    const float* x = (const float*)d_in[0];   // [B, R, I]
    const float* W = (const float*)d_in[1];   // [R, C, O, I]
    float* out = (float*)d_out;               // [B, C, O, 1] flat = 12800
    float* ws = (float*)d_ws;

    // Workspace (floats): v[SOUT] | b1[RN*CN] | Zp[NRC*32] | Sp[NRC*SOUT] | U
    float* v  = ws;
    float* b1 = v + SOUT;
    float* Zp = b1 + (size_t)RN * CN;
    float* Sp = Zp + (size_t)NRC * 32;
    uint32_t* U = (uint32_t*)(Sp + (size_t)NRC * SOUT);   // 327.7 MB bf16 u_hat

    dim3 blk(320), grid(5, NRC), fg(NFIN);

    // it 0: u = W·x (store bf16 nt), S0 partials; v0 = squash(S0/RN)
    caps_pass0<<<grid, blk, 0, stream>>>(x, W, Sp, U);
    caps_fin<0><<<fg, blk, 0, stream>>>(Sp, Zp, v);
    // it 1: b1 = mean_b<u,v0> (store); S1,Z1 partials; v1 = squash(S1/z1)
    caps_passU<1><<<grid, blk, 0, stream>>>(U, v, nullptr, b1, Sp, Zp);
    caps_fin<1><<<fg, blk, 0, stream>>>(Sp, Zp, v);
    // it 2: b2 = b1 + mean_b<u,v1>; S2,Z2 partials; out = squash(S2/z2)
    caps_passU<2><<<grid, blk, 0, stream>>>(U, v, b1, nullptr, Sp, Zp);
    caps_fin<2><<<fg, blk, 0, stream>>>(Sp, Zp, out);
}